// Round 10
// baseline (76.526 us; speedup 1.0000x reference)
//
#include <hip/hip_runtime.h>
#include <stdint.h>

typedef _Float16 f16x8 __attribute__((ext_vector_type(8)));
typedef float    f32x4 __attribute__((ext_vector_type(4)));

#define H 56
#define W 56
#define C_IN 32
#define N_OUT 64
#define CP 40                 // c-dim padded to 40 halves: col stride 80 B (16B-aligned,
                              // 20-dword stride -> uniform banks on b128 frag reads)

__device__ __forceinline__ float q16f(float v) { return (float)(_Float16)v; }

// ONE kernel: per-block weight-frag pack (LDS) + x-window stage (LDS) + 9-shift
// K=32 MFMA GEMM. No intermediate tensors, no extra launches.
__global__ __launch_bounds__(256, 3) void conv_fused(
    const float* __restrict__ x,        // [16,32,56,56]
    const float* __restrict__ weight,   // [64,32,3,3]
    const float* __restrict__ bias,     // [64]
    float* __restrict__ out)            // [16,64,56,56]
{
    __shared__ __align__(16) uint32_t sW[9216];          // 36,864 B: A-frags
    __shared__ __align__(16) _Float16 sX[6 * 34 * CP];   // 16,320 B: [r][col][c]

    const int tid = threadIdx.x;
    const int b   = blockIdx.z;
    const int oh0 = blockIdx.y * 4;
    const int bx  = blockIdx.x;
    const int ow0 = bx * 24;            // tiles cover ow 0-31 and 24-55 (overlap masked)

    // ---- Phase A: pack weight A-frags into LDS ----
    // dword o = ((ij*4+nt)*64 + lane)*4 + t2:
    //   A[m = nt*16 + (lane&15) -> n][k = (lane>>4)*8 + 2*t2 + {0,1} -> c]
    #pragma unroll
    for (int k = 0; k < 36; ++k) {
        int o    = k * 256 + tid;       // < 9216
        int t2   = o & 3;
        int lane = (o >> 2) & 63;
        int u    = o >> 8;              // ij*4 + nt
        int nt   = u & 3, ij = u >> 2;
        int n    = nt * 16 + (lane & 15);
        int c0   = (lane >> 4) * 8 + 2 * t2;
        const float* ws = weight + n * 288 + c0 * 9 + ij;
        _Float16 lo = (_Float16)ws[0];
        _Float16 hi = (_Float16)ws[9];
        sW[o] = (uint32_t)__builtin_bit_cast(uint16_t, lo) |
                ((uint32_t)__builtin_bit_cast(uint16_t, hi) << 16);
    }

    // ---- Phase B: stage x window: c 0..31, r 0..5 (ih=oh0+r-1), col 0..33 (iw=ow0+col-1)
    // col is the fast lane index -> coalesced global runs of 34 dwords.
    #pragma unroll
    for (int k = 0; k < 26; ++k) {
        int f = k * 256 + tid;
        if (f < 6528) {
            int col = f % 34;
            int u   = f / 34;           // c*6 + r
            int r   = u % 6;
            int c   = u / 6;
            int ih = oh0 + r - 1, iw = ow0 + col - 1;
            float v = 0.f;
            if ((unsigned)ih < (unsigned)H && (unsigned)iw < (unsigned)W)
                v = x[((b * C_IN + c) * H + ih) * W + iw];
            sX[(r * 34 + col) * CP + c] = (_Float16)v;
        }
    }
    __syncthreads();

    // ---- Phase C: 9 shifted K=32 GEMMs ----
    const int wid  = tid >> 6;          // oh row 0..3
    const int lane = tid & 63;
    const int quad = lane >> 4;
    const int px   = lane & 15;
    const int oh   = oh0 + wid;

    f32x4 acc[2][4] = {{{0,0,0,0},{0,0,0,0},{0,0,0,0},{0,0,0,0}},
                       {{0,0,0,0},{0,0,0,0},{0,0,0,0},{0,0,0,0}}};
    const f16x8* wfrag = (const f16x8*)sW;

    #pragma unroll
    for (int ij = 0; ij < 9; ++ij) {
        const int i = ij / 3, jj = ij - 3 * i;
        // B[k=c][n=px]: 16 contiguous bytes at 16B-aligned offset (col stride 80 B)
        const _Float16* xb = &sX[((wid + i) * 34 + px + jj) * CP + quad * 8];
        f16x8 xf0 = *(const f16x8*)xb;                  // ds_read_b128
        f16x8 xf1 = *(const f16x8*)(xb + 16 * CP);
        #pragma unroll
        for (int nt = 0; nt < 4; ++nt) {
            f16x8 wv = wfrag[(ij * 4 + nt) * 64 + lane]; // ds_read_b128, contiguous
            acc[0][nt] = __builtin_amdgcn_mfma_f32_16x16x32_f16(wv, xf0, acc[0][nt], 0, 0, 0);
            acc[1][nt] = __builtin_amdgcn_mfma_f32_16x16x32_f16(wv, xf1, acc[1][nt], 0, 0, 0);
        }
    }

    // ---- epilogue: out = q16(acc + q16(bias)); quarter-wave = one full 64B line.
    // overlap columns 24..31 owned by tile bx==0.
    #pragma unroll
    for (int xg = 0; xg < 2; ++xg) {
        const int ow = ow0 + 16 * xg + px;
        if (bx == 0 || ow >= 32) {
            #pragma unroll
            for (int nt = 0; nt < 4; ++nt) {
                #pragma unroll
                for (int reg = 0; reg < 4; ++reg) {
                    const int n = nt * 16 + quad * 4 + reg;
                    out[((size_t)(b * N_OUT + n) * H + oh) * W + ow] =
                        q16f(acc[xg][nt][reg] + q16f(bias[n]));
                }
            }
        }
    }
}

extern "C" void kernel_launch(void* const* d_in, const int* in_sizes, int n_in,
                              void* d_out, int out_size, void* d_ws, size_t ws_size,
                              hipStream_t stream) {
    const float* x      = (const float*)d_in[0];
    const float* weight = (const float*)d_in[1];
    const float* bias   = (const float*)d_in[2];
    float* out          = (float*)d_out;

    conv_fused<<<dim3(2, 14, 16), dim3(256), 0, stream>>>(x, weight, bias, out);
}